// Round 5
// baseline (282.557 us; speedup 1.0000x reference)
//
#include <hip/hip_runtime.h>

// NetVLAD fused kernel for MI355X (gfx950).
// Shapes: x[N=64][C=128][S=4096] fp32, conv_w[K=64][C=128], centroids[K=64][C=128].
// out[N][K*C] fp32.
//
// R5 = R4 structure with the grid reverted to the empirically-best 512 blocks
// (P=8, CH=8; 1024-block grids regressed ~+40us twice: per-block fixed costs,
// tail wave, worse L3 on x) + prefetch depth 2 (loads issued 2 chunks ahead,
// ~2 chunk-bodies of slack vs ~900cyc cold-miss latency).
//  - lgkm-only barriers: register-bound global prefetch survives s_barrier
//  - P1 B-frags built in registers from rotated x_cs column reads (no x_sc)
//  - x_cs double-buffered: 2 barriers/chunk
//  - partial-sum outputs (no atomics, no memset); atomic fallback kept

#define Nn 64
#define Cc 128
#define Ss 4096
#define Kk 64
#define TS 64
#define CH 8
#define SB (TS*CH)
#define Pp 8    // s-slabs == partial buffers

typedef __attribute__((ext_vector_type(8))) short bf16x8;
typedef __attribute__((ext_vector_type(4))) float f32x4;

__device__ __forceinline__ unsigned f2bf(float f) {
  unsigned u = __float_as_uint(f);
  u = (u + 0x7FFFu + ((u >> 16) & 1u)) >> 16;  // RNE
  return u;
}

// Barrier that waits only LDS ops (lgkmcnt), NOT in-flight global loads (vmcnt).
// Correct: cross-wave communication is exclusively through LDS; global loads
// land in private registers.
__device__ __forceinline__ void bar_lds() {
  asm volatile("s_waitcnt lgkmcnt(0)\n\ts_barrier" ::: "memory");
}

// LDS strides in halves. Rows 144B (multiple of 16B) for aligned b128 access.
#define XCS_STR 72    // x_cs[2][128][72]
#define AKS_STR 72    // a_ks[64][72]

__launch_bounds__(256, 2)
__global__ void netvlad_main(const float* __restrict__ x,
                             const float* __restrict__ w,
                             float* __restrict__ vlad,   // [P][N][K][C] partials, or [N][K][C] zeroed (atomic)
                             float* __restrict__ asum,   // [P][N][K] partials,    or [N][K] zeroed (atomic)
                             int use_atomic)
{
  __shared__ __align__(16) unsigned short x_cs[2][Cc][XCS_STR];  // x[c][s], double-buffered
  __shared__ __align__(16) unsigned short a_ks[Kk][AKS_STR];     // a[k][s]

  const int t   = threadIdx.x;
  const int wv  = t >> 6;          // wave 0..3
  const int l15 = t & 15;
  const int l4  = (t >> 4) & 3;    // lane quad within wave
  const int n   = blockIdx.y;
  const int sb  = blockIdx.x;      // s-slab 0..7
  const size_t xbase = (size_t)n * Cc * Ss;

  // ---- preload W fragments into registers (A-operand of P1) ----
  // A[m=k][kd=c]: lane holds A[16*mt + l15][32*q + 8*l4 + j], j=0..7
  bf16x8 wfrag[4][4];
#pragma unroll
  for (int mt = 0; mt < 4; ++mt) {
#pragma unroll
    for (int q = 0; q < 4; ++q) {
      const float* wp = w + (16*mt + l15) * Cc + 32*q + 8*l4;
      float4 a = *(const float4*)wp;
      float4 b = *(const float4*)(wp + 4);
      bf16x8 f;
      f[0] = (short)f2bf(a.x); f[1] = (short)f2bf(a.y);
      f[2] = (short)f2bf(a.z); f[3] = (short)f2bf(a.w);
      f[4] = (short)f2bf(b.x); f[5] = (short)f2bf(b.y);
      f[6] = (short)f2bf(b.z); f[7] = (short)f2bf(b.w);
      wfrag[mt][q] = f;
    }
  }

  // persistent accumulators
  f32x4 acc3[4][2];                 // [mt(k-tile)][tc(c-tile within wave's 32c)]
#pragma unroll
  for (int mt = 0; mt < 4; ++mt)
#pragma unroll
    for (int tc = 0; tc < 2; ++tc) acc3[mt][tc] = (f32x4){0.f,0.f,0.f,0.f};
  float asum_reg[4][4];             // [mt][r]
#pragma unroll
  for (int mt = 0; mt < 4; ++mt)
#pragma unroll
    for (int r = 0; r < 4; ++r) asum_reg[mt][r] = 0.f;

  // ---- prologue: prefetch chunks 0 and 1 into registers (depth 2) ----
  const int s4 = 4 * l15;
  const int cb = t >> 4;           // 0..15
  const float* px0 = x + xbase + (size_t)cb * Ss + sb * SB + s4;
  float4 v[2][8];
#pragma unroll
  for (int it = 0; it < 8; ++it)
    v[0][it] = *(const float4*)(px0 + (size_t)(16 * it) * Ss);
#pragma unroll
  for (int it = 0; it < 8; ++it)
    v[1][it] = *(const float4*)(px0 + TS + (size_t)(16 * it) * Ss);

  for (int ch = 0; ch < CH; ++ch) {
    const int buf = ch & 1;

    // ---- convert prefetched regs (issued at ch-2) -> x_cs[buf] bf16 ----
#pragma unroll
    for (int it = 0; it < 8; ++it) {
      float4 vv = v[buf][it];
      unsigned p0 = f2bf(vv.x) | (f2bf(vv.y) << 16);
      unsigned p1 = f2bf(vv.z) | (f2bf(vv.w) << 16);
      *(int2*)&x_cs[buf][cb + 16*it][s4] = make_int2((int)p0, (int)p1);
    }
    // ---- issue loads for chunk ch+2 into the slot just consumed ----
    if (ch + 2 < CH) {
      const float* px = px0 + (ch + 2) * TS;
#pragma unroll
      for (int it = 0; it < 8; ++it)
        v[buf][it] = *(const float4*)(px + (size_t)(16 * it) * Ss);
    }
    bar_lds();   // BA: x_cs[buf] visible; prior a_ks readers drained

    // ---- build P1 B-frags directly in registers from x_cs[buf] columns ----
    // bfr[q][j'] = x[c = 32q + 8*l4 + j'][s = 16*wv + l15]
    // rotation (i+2*l4)&7 -> each instruction's 64 lanes tile all 32 banks
    bf16x8 bfr[4];
#pragma unroll
    for (int j = 0; j < 4; ++j) {
      const int c8 = 32*j + 8*l4;
      unsigned short h[8];
#pragma unroll
      for (int i = 0; i < 8; ++i) {
        const int i2 = (i + 2*l4) & 7;
        h[i2] = x_cs[buf][c8 + i2][16*wv + l15];
      }
      bf16x8 f;
#pragma unroll
      for (int i = 0; i < 8; ++i) f[i] = (short)h[i];
      bfr[j] = f;
    }

    // ---- P1: logits tile. wave wv owns s-tile [16*wv,16*wv+16), all 64 k ----
    f32x4 acc1[4];
#pragma unroll
    for (int mt = 0; mt < 4; ++mt) acc1[mt] = (f32x4){0.f,0.f,0.f,0.f};
#pragma unroll
    for (int q = 0; q < 4; ++q) {
#pragma unroll
      for (int mt = 0; mt < 4; ++mt)
        acc1[mt] = __builtin_amdgcn_mfma_f32_16x16x32_bf16(wfrag[mt][q], bfr[q], acc1[mt], 0, 0, 0);
    }

    // ---- softmax over k, fully in-wave ----
    // C/D layout: col s = 16*wv + l15, row k = 16*mt + 4*l4 + r
    float e[4][4];
    float cs = 0.f;
#pragma unroll
    for (int mt = 0; mt < 4; ++mt)
#pragma unroll
      for (int r = 0; r < 4; ++r) {
        float ev = __expf(acc1[mt][r]);
        e[mt][r] = ev;
        cs += ev;
      }
    cs += __shfl_xor(cs, 16, 64);
    cs += __shfl_xor(cs, 32, 64);
    const float inv = 1.0f / cs;
#pragma unroll
    for (int mt = 0; mt < 4; ++mt)
#pragma unroll
      for (int r = 0; r < 4; ++r) {
        float an = e[mt][r] * inv;
        asum_reg[mt][r] += an;
        a_ks[16*mt + 4*l4 + r][16*wv + l15] = (unsigned short)f2bf(an);
      }
    bar_lds();   // BB: a_ks ready

    // ---- P3: vlad += A @ X^T. wave wv owns c in [32*wv, 32*wv+32) ----
#pragma unroll
    for (int q2 = 0; q2 < 2; ++q2) {
      bf16x8 afr[4];
#pragma unroll
      for (int mt = 0; mt < 4; ++mt)
        afr[mt] = *(bf16x8*)&a_ks[16*mt + l15][32*q2 + 8*l4];
#pragma unroll
      for (int tc = 0; tc < 2; ++tc) {
        bf16x8 bfx = *(bf16x8*)&x_cs[buf][32*wv + 16*tc + l15][32*q2 + 8*l4];
#pragma unroll
        for (int mt = 0; mt < 4; ++mt)
          acc3[mt][tc] = __builtin_amdgcn_mfma_f32_16x16x32_bf16(afr[mt], bfx, acc3[mt][tc], 0, 0, 0);
      }
    }
    // no end-of-chunk barrier: next convert writes x_cs[1-buf]; rewrites of
    // x_cs[buf] (ch+2) and a_ks (ch+1) are fenced by BA/BB of chunk ch+1.
  }

  // ---- block epilogue: asum cross-wave reduction via LDS, then stores ----
  bar_lds();                    // all P3 a_ks reads drained before reuse
  float* asml = (float*)a_ks;
#pragma unroll
  for (int mt = 0; mt < 4; ++mt) {
#pragma unroll
    for (int r = 0; r < 4; ++r) {
      float vv = asum_reg[mt][r];
      vv += __shfl_xor(vv, 1, 64);
      vv += __shfl_xor(vv, 2, 64);
      vv += __shfl_xor(vv, 4, 64);
      vv += __shfl_xor(vv, 8, 64);
      if (l15 == 0) asml[wv * Kk + 16*mt + 4*l4 + r] = vv;
    }
  }
  bar_lds();
  if (t < Kk) {
    float s = asml[t] + asml[Kk + t] + asml[2*Kk + t] + asml[3*Kk + t];
    if (use_atomic) atomicAdd(&asum[n * Kk + t], s);
    else            asum[((size_t)sb * Nn + n) * Kk + t] = s;
  }

  if (use_atomic) {
#pragma unroll
    for (int mt = 0; mt < 4; ++mt)
#pragma unroll
      for (int tc = 0; tc < 2; ++tc)
#pragma unroll
        for (int r = 0; r < 4; ++r) {
          const int k = 16*mt + 4*l4 + r;
          const int c = 32*wv + 16*tc + l15;
          atomicAdd(&vlad[((size_t)n * Kk + k) * Cc + c], acc3[mt][tc][r]);
        }
  } else {
    float* vp = vlad + ((size_t)sb * Nn + n) * (Kk * Cc);
#pragma unroll
    for (int mt = 0; mt < 4; ++mt)
#pragma unroll
      for (int tc = 0; tc < 2; ++tc)
#pragma unroll
        for (int r = 0; r < 4; ++r) {
          const int k = 16*mt + 4*l4 + r;
          const int c = 32*wv + 16*tc + l15;
          vp[k * Cc + c] = acc3[mt][tc][r];   // streaming, coalesced per 16 lanes
        }
  }
}

__global__ void netvlad_epilogue(const float* __restrict__ vlad,  // [P][N][K][C] or [N][K][C]
                                 const float* __restrict__ asum,  // [P][N][K]    or [N][K]
                                 const float* __restrict__ cent,
                                 float* __restrict__ out,
                                 int nparts)
{
  const int n  = blockIdx.x;
  const int k  = 16*blockIdx.y + (threadIdx.x >> 4);
  const int cq = threadIdx.x & 15;   // 16 threads per k, 8 c each

  float ak = 0.f;
  float4 x0 = make_float4(0.f, 0.f, 0.f, 0.f);
  float4 x1 = make_float4(0.f, 0.f, 0.f, 0.f);
  for (int p = 0; p < nparts; ++p) {
    ak += asum[((size_t)p * Nn + n) * Kk + k];
    const float* vp = vlad + (((size_t)p * Nn + n) * Kk + k) * Cc + 8*cq;
    float4 a0 = *(const float4*)vp;
    float4 a1 = *(const float4*)(vp + 4);
    x0.x += a0.x; x0.y += a0.y; x0.z += a0.z; x0.w += a0.w;
    x1.x += a1.x; x1.y += a1.y; x1.z += a1.z; x1.w += a1.w;
  }

  const size_t cbse = (size_t)k * Cc + 8*cq;
  float4 c0 = *(const float4*)(cent + cbse);
  float4 c1 = *(const float4*)(cent + cbse + 4);
  float4 r0, r1;
  r0.x = x0.x - ak*c0.x; r0.y = x0.y - ak*c0.y; r0.z = x0.z - ak*c0.z; r0.w = x0.w - ak*c0.w;
  r1.x = x1.x - ak*c1.x; r1.y = x1.y - ak*c1.y; r1.z = x1.z - ak*c1.z; r1.w = x1.w - ak*c1.w;
  float ss = r0.x*r0.x + r0.y*r0.y + r0.z*r0.z + r0.w*r0.w
           + r1.x*r1.x + r1.y*r1.y + r1.z*r1.z + r1.w*r1.w;
  ss += __shfl_xor(ss, 1, 64);
  ss += __shfl_xor(ss, 2, 64);
  ss += __shfl_xor(ss, 4, 64);
  ss += __shfl_xor(ss, 8, 64);
  // intra-norm; global norm is exactly sqrt(K)=8 since rows are unit norm
  const float rn = rsqrtf(ss) * 0.125f;
  r0.x *= rn; r0.y *= rn; r0.z *= rn; r0.w *= rn;
  r1.x *= rn; r1.y *= rn; r1.z *= rn; r1.w *= rn;
  float* op = out + (size_t)n * (Kk * Cc) + (size_t)k * Cc + 8*cq;
  *(float4*)op = r0;
  *(float4*)(op + 4) = r1;
}

extern "C" void kernel_launch(void* const* d_in, const int* in_sizes, int n_in,
                              void* d_out, int out_size, void* d_ws, size_t ws_size,
                              hipStream_t stream)
{
  const float* x    = (const float*)d_in[0];
  const float* w    = (const float*)d_in[1];
  const float* cent = (const float*)d_in[2];
  float* out = (float*)d_out;

  const size_t vlad_elems_p = (size_t)Pp * Nn * Kk * Cc;
  const size_t asum_elems_p = (size_t)Pp * Nn * Kk;
  const size_t need = (vlad_elems_p + asum_elems_p) * sizeof(float);

  if (ws_size >= need) {
    // partial-sum path: no atomics, no memset
    float* vlad_part = (float*)d_ws;
    float* asum_part = vlad_part + vlad_elems_p;
    netvlad_main<<<dim3(Pp, Nn), 256, 0, stream>>>(x, w, vlad_part, asum_part, 0);
    netvlad_epilogue<<<dim3(Nn, 4), 256, 0, stream>>>(vlad_part, asum_part, cent, out, Pp);
  } else {
    // atomic fallback
    float* vlad = (float*)d_ws;
    float* asum = vlad + (size_t)Nn * Kk * Cc;
    const size_t zbytes = ((size_t)Nn * Kk * Cc + (size_t)Nn * Kk) * sizeof(float);
    hipMemsetAsync(d_ws, 0, zbytes, stream);
    netvlad_main<<<dim3(Pp, Nn), 256, 0, stream>>>(x, w, vlad, asum, 1);
    netvlad_epilogue<<<dim3(Nn, 4), 256, 0, stream>>>(vlad, asum, cent, out, 1);
  }
}

// Round 6
// 209.799 us; speedup vs baseline: 1.3468x; 1.3468x over previous
//
#include <hip/hip_runtime.h>

// NetVLAD fused kernel for MI355X (gfx950).
// Shapes: x[N=64][C=128][S=4096] fp32, conv_w[K=64][C=128], centroids[K=64][C=128].
// out[N][K*C] fp32.
//
// R6 = R4 structure at the empirically-best 512-block grid (P=8, CH=8).
// R5's regression was diagnosed as scratch spill: v[2][8] indexed by buf=ch&1
// in a non-unrolled loop -> private-memory demotion -> 134 MB scratch traffic
// (WRITE_SIZE 146 MB vs 17 MB expected). R6 uses the scratch-safe single v[8]
// (constant indices only, proven register-resident in R4 at VGPR=84).
//  - lgkm-only barriers: register-bound global prefetch survives s_barrier
//  - P1 B-frags built in registers from rotated x_cs column reads (no x_sc)
//  - x_cs double-buffered: 2 barriers/chunk
//  - partial-sum outputs (no atomics, no memset); atomic fallback kept

#define Nn 64
#define Cc 128
#define Ss 4096
#define Kk 64
#define TS 64
#define CH 8
#define SB (TS*CH)
#define Pp 8    // s-slabs == partial buffers

typedef __attribute__((ext_vector_type(8))) short bf16x8;
typedef __attribute__((ext_vector_type(4))) float f32x4;

__device__ __forceinline__ unsigned f2bf(float f) {
  unsigned u = __float_as_uint(f);
  u = (u + 0x7FFFu + ((u >> 16) & 1u)) >> 16;  // RNE
  return u;
}

// Barrier that waits only LDS ops (lgkmcnt), NOT in-flight global loads (vmcnt).
// Correct: cross-wave communication is exclusively through LDS; global loads
// land in private registers.
__device__ __forceinline__ void bar_lds() {
  asm volatile("s_waitcnt lgkmcnt(0)\n\ts_barrier" ::: "memory");
}

// LDS strides in halves. Rows 144B (multiple of 16B) for aligned b128 access.
#define XCS_STR 72    // x_cs[2][128][72]
#define AKS_STR 72    // a_ks[64][72]

__launch_bounds__(256, 2)
__global__ void netvlad_main(const float* __restrict__ x,
                             const float* __restrict__ w,
                             float* __restrict__ vlad,   // [P][N][K][C] partials, or [N][K][C] zeroed (atomic)
                             float* __restrict__ asum,   // [P][N][K] partials,    or [N][K] zeroed (atomic)
                             int use_atomic)
{
  __shared__ __align__(16) unsigned short x_cs[2][Cc][XCS_STR];  // x[c][s], double-buffered
  __shared__ __align__(16) unsigned short a_ks[Kk][AKS_STR];     // a[k][s]

  const int t   = threadIdx.x;
  const int wv  = t >> 6;          // wave 0..3
  const int l15 = t & 15;
  const int l4  = (t >> 4) & 3;    // lane quad within wave
  const int n   = blockIdx.y;
  const int sb  = blockIdx.x;      // s-slab 0..7
  const size_t xbase = (size_t)n * Cc * Ss;

  // ---- preload W fragments into registers (A-operand of P1) ----
  // A[m=k][kd=c]: lane holds A[16*mt + l15][32*q + 8*l4 + j], j=0..7
  bf16x8 wfrag[4][4];
#pragma unroll
  for (int mt = 0; mt < 4; ++mt) {
#pragma unroll
    for (int q = 0; q < 4; ++q) {
      const float* wp = w + (16*mt + l15) * Cc + 32*q + 8*l4;
      float4 a = *(const float4*)wp;
      float4 b = *(const float4*)(wp + 4);
      bf16x8 f;
      f[0] = (short)f2bf(a.x); f[1] = (short)f2bf(a.y);
      f[2] = (short)f2bf(a.z); f[3] = (short)f2bf(a.w);
      f[4] = (short)f2bf(b.x); f[5] = (short)f2bf(b.y);
      f[6] = (short)f2bf(b.z); f[7] = (short)f2bf(b.w);
      wfrag[mt][q] = f;
    }
  }

  // persistent accumulators
  f32x4 acc3[4][2];                 // [mt(k-tile)][tc(c-tile within wave's 32c)]
#pragma unroll
  for (int mt = 0; mt < 4; ++mt)
#pragma unroll
    for (int tc = 0; tc < 2; ++tc) acc3[mt][tc] = (f32x4){0.f,0.f,0.f,0.f};
  float asum_reg[4][4];             // [mt][r]
#pragma unroll
  for (int mt = 0; mt < 4; ++mt)
#pragma unroll
    for (int r = 0; r < 4; ++r) asum_reg[mt][r] = 0.f;

  // ---- prologue: prefetch chunk 0 into registers (constant-indexed v[8]) ----
  const int s4 = 4 * l15;
  const int cb = t >> 4;           // 0..15
  const float* px0 = x + xbase + (size_t)cb * Ss + sb * SB + s4;
  float4 v[8];
#pragma unroll
  for (int it = 0; it < 8; ++it)
    v[it] = *(const float4*)(px0 + (size_t)(16 * it) * Ss);

  for (int ch = 0; ch < CH; ++ch) {
    const int buf = ch & 1;

    // ---- convert prefetched regs -> x_cs[buf] bf16 ([c][s]) ----
#pragma unroll
    for (int it = 0; it < 8; ++it) {
      float4 vv = v[it];
      unsigned p0 = f2bf(vv.x) | (f2bf(vv.y) << 16);
      unsigned p1 = f2bf(vv.z) | (f2bf(vv.w) << 16);
      *(int2*)&x_cs[buf][cb + 16*it][s4] = make_int2((int)p0, (int)p1);
    }
    // ---- issue next chunk's loads; they stay in flight across bar_lds ----
    if (ch + 1 < CH) {
      const float* px = px0 + (ch + 1) * TS;
#pragma unroll
      for (int it = 0; it < 8; ++it)
        v[it] = *(const float4*)(px + (size_t)(16 * it) * Ss);
    }
    bar_lds();   // BA: x_cs[buf] visible; prior a_ks readers drained

    // ---- build P1 B-frags directly in registers from x_cs[buf] columns ----
    // bfr[q][j'] = x[c = 32q + 8*l4 + j'][s = 16*wv + l15]
    // rotation (i+2*l4)&7 -> each instruction's 64 lanes tile all 32 banks
    bf16x8 bfr[4];
#pragma unroll
    for (int j = 0; j < 4; ++j) {
      const int c8 = 32*j + 8*l4;
      unsigned short h[8];
#pragma unroll
      for (int i = 0; i < 8; ++i) {
        const int i2 = (i + 2*l4) & 7;
        h[i2] = x_cs[buf][c8 + i2][16*wv + l15];
      }
      bf16x8 f;
#pragma unroll
      for (int i = 0; i < 8; ++i) f[i] = (short)h[i];
      bfr[j] = f;
    }

    // ---- P1: logits tile. wave wv owns s-tile [16*wv,16*wv+16), all 64 k ----
    f32x4 acc1[4];
#pragma unroll
    for (int mt = 0; mt < 4; ++mt) acc1[mt] = (f32x4){0.f,0.f,0.f,0.f};
#pragma unroll
    for (int q = 0; q < 4; ++q) {
#pragma unroll
      for (int mt = 0; mt < 4; ++mt)
        acc1[mt] = __builtin_amdgcn_mfma_f32_16x16x32_bf16(wfrag[mt][q], bfr[q], acc1[mt], 0, 0, 0);
    }

    // ---- softmax over k, fully in-wave ----
    // C/D layout: col s = 16*wv + l15, row k = 16*mt + 4*l4 + r
    float e[4][4];
    float cs = 0.f;
#pragma unroll
    for (int mt = 0; mt < 4; ++mt)
#pragma unroll
      for (int r = 0; r < 4; ++r) {
        float ev = __expf(acc1[mt][r]);
        e[mt][r] = ev;
        cs += ev;
      }
    cs += __shfl_xor(cs, 16, 64);
    cs += __shfl_xor(cs, 32, 64);
    const float inv = 1.0f / cs;
#pragma unroll
    for (int mt = 0; mt < 4; ++mt)
#pragma unroll
      for (int r = 0; r < 4; ++r) {
        float an = e[mt][r] * inv;
        asum_reg[mt][r] += an;
        a_ks[16*mt + 4*l4 + r][16*wv + l15] = (unsigned short)f2bf(an);
      }
    bar_lds();   // BB: a_ks ready

    // ---- P3: vlad += A @ X^T. wave wv owns c in [32*wv, 32*wv+32) ----
#pragma unroll
    for (int q2 = 0; q2 < 2; ++q2) {
      bf16x8 afr[4];
#pragma unroll
      for (int mt = 0; mt < 4; ++mt)
        afr[mt] = *(bf16x8*)&a_ks[16*mt + l15][32*q2 + 8*l4];
#pragma unroll
      for (int tc = 0; tc < 2; ++tc) {
        bf16x8 bfx = *(bf16x8*)&x_cs[buf][32*wv + 16*tc + l15][32*q2 + 8*l4];
#pragma unroll
        for (int mt = 0; mt < 4; ++mt)
          acc3[mt][tc] = __builtin_amdgcn_mfma_f32_16x16x32_bf16(afr[mt], bfx, acc3[mt][tc], 0, 0, 0);
      }
    }
    // no end-of-chunk barrier: next convert writes x_cs[1-buf]; rewrites of
    // x_cs[buf] (ch+2) and a_ks (ch+1) are fenced by BA/BB of chunk ch+1.
  }

  // ---- block epilogue: asum cross-wave reduction via LDS, then stores ----
  bar_lds();                    // all P3 a_ks reads drained before reuse
  float* asml = (float*)a_ks;
#pragma unroll
  for (int mt = 0; mt < 4; ++mt) {
#pragma unroll
    for (int r = 0; r < 4; ++r) {
      float vv = asum_reg[mt][r];
      vv += __shfl_xor(vv, 1, 64);
      vv += __shfl_xor(vv, 2, 64);
      vv += __shfl_xor(vv, 4, 64);
      vv += __shfl_xor(vv, 8, 64);
      if (l15 == 0) asml[wv * Kk + 16*mt + 4*l4 + r] = vv;
    }
  }
  bar_lds();
  if (t < Kk) {
    float s = asml[t] + asml[Kk + t] + asml[2*Kk + t] + asml[3*Kk + t];
    if (use_atomic) atomicAdd(&asum[n * Kk + t], s);
    else            asum[((size_t)sb * Nn + n) * Kk + t] = s;
  }

  if (use_atomic) {
#pragma unroll
    for (int mt = 0; mt < 4; ++mt)
#pragma unroll
      for (int tc = 0; tc < 2; ++tc)
#pragma unroll
        for (int r = 0; r < 4; ++r) {
          const int k = 16*mt + 4*l4 + r;
          const int c = 32*wv + 16*tc + l15;
          atomicAdd(&vlad[((size_t)n * Kk + k) * Cc + c], acc3[mt][tc][r]);
        }
  } else {
    float* vp = vlad + ((size_t)sb * Nn + n) * (Kk * Cc);
#pragma unroll
    for (int mt = 0; mt < 4; ++mt)
#pragma unroll
      for (int tc = 0; tc < 2; ++tc)
#pragma unroll
        for (int r = 0; r < 4; ++r) {
          const int k = 16*mt + 4*l4 + r;
          const int c = 32*wv + 16*tc + l15;
          vp[k * Cc + c] = acc3[mt][tc][r];   // streaming, coalesced per 16 lanes
        }
  }
}

__global__ void netvlad_epilogue(const float* __restrict__ vlad,  // [P][N][K][C] or [N][K][C]
                                 const float* __restrict__ asum,  // [P][N][K]    or [N][K]
                                 const float* __restrict__ cent,
                                 float* __restrict__ out,
                                 int nparts)
{
  const int n  = blockIdx.x;
  const int k  = 16*blockIdx.y + (threadIdx.x >> 4);
  const int cq = threadIdx.x & 15;   // 16 threads per k, 8 c each

  float ak = 0.f;
  float4 x0 = make_float4(0.f, 0.f, 0.f, 0.f);
  float4 x1 = make_float4(0.f, 0.f, 0.f, 0.f);
  for (int p = 0; p < nparts; ++p) {
    ak += asum[((size_t)p * Nn + n) * Kk + k];
    const float* vp = vlad + (((size_t)p * Nn + n) * Kk + k) * Cc + 8*cq;
    float4 a0 = *(const float4*)vp;
    float4 a1 = *(const float4*)(vp + 4);
    x0.x += a0.x; x0.y += a0.y; x0.z += a0.z; x0.w += a0.w;
    x1.x += a1.x; x1.y += a1.y; x1.z += a1.z; x1.w += a1.w;
  }

  const size_t cbse = (size_t)k * Cc + 8*cq;
  float4 c0 = *(const float4*)(cent + cbse);
  float4 c1 = *(const float4*)(cent + cbse + 4);
  float4 r0, r1;
  r0.x = x0.x - ak*c0.x; r0.y = x0.y - ak*c0.y; r0.z = x0.z - ak*c0.z; r0.w = x0.w - ak*c0.w;
  r1.x = x1.x - ak*c1.x; r1.y = x1.y - ak*c1.y; r1.z = x1.z - ak*c1.z; r1.w = x1.w - ak*c1.w;
  float ss = r0.x*r0.x + r0.y*r0.y + r0.z*r0.z + r0.w*r0.w
           + r1.x*r1.x + r1.y*r1.y + r1.z*r1.z + r1.w*r1.w;
  ss += __shfl_xor(ss, 1, 64);
  ss += __shfl_xor(ss, 2, 64);
  ss += __shfl_xor(ss, 4, 64);
  ss += __shfl_xor(ss, 8, 64);
  // intra-norm; global norm is exactly sqrt(K)=8 since rows are unit norm
  const float rn = rsqrtf(ss) * 0.125f;
  r0.x *= rn; r0.y *= rn; r0.z *= rn; r0.w *= rn;
  r1.x *= rn; r1.y *= rn; r1.z *= rn; r1.w *= rn;
  float* op = out + (size_t)n * (Kk * Cc) + (size_t)k * Cc + 8*cq;
  *(float4*)op = r0;
  *(float4*)(op + 4) = r1;
}

extern "C" void kernel_launch(void* const* d_in, const int* in_sizes, int n_in,
                              void* d_out, int out_size, void* d_ws, size_t ws_size,
                              hipStream_t stream)
{
  const float* x    = (const float*)d_in[0];
  const float* w    = (const float*)d_in[1];
  const float* cent = (const float*)d_in[2];
  float* out = (float*)d_out;

  const size_t vlad_elems_p = (size_t)Pp * Nn * Kk * Cc;
  const size_t asum_elems_p = (size_t)Pp * Nn * Kk;
  const size_t need = (vlad_elems_p + asum_elems_p) * sizeof(float);

  if (ws_size >= need) {
    // partial-sum path: no atomics, no memset
    float* vlad_part = (float*)d_ws;
    float* asum_part = vlad_part + vlad_elems_p;
    netvlad_main<<<dim3(Pp, Nn), 256, 0, stream>>>(x, w, vlad_part, asum_part, 0);
    netvlad_epilogue<<<dim3(Nn, 4), 256, 0, stream>>>(vlad_part, asum_part, cent, out, Pp);
  } else {
    // atomic fallback
    float* vlad = (float*)d_ws;
    float* asum = vlad + (size_t)Nn * Kk * Cc;
    const size_t zbytes = ((size_t)Nn * Kk * Cc + (size_t)Nn * Kk) * sizeof(float);
    hipMemsetAsync(d_ws, 0, zbytes, stream);
    netvlad_main<<<dim3(Pp, Nn), 256, 0, stream>>>(x, w, vlad, asum, 1);
    netvlad_epilogue<<<dim3(Nn, 4), 256, 0, stream>>>(vlad, asum, cent, out, 1);
  }
}